// Round 1
// baseline (392.402 us; speedup 1.0000x reference)
//
#include <hip/hip_runtime.h>
#include <math.h>

typedef unsigned int u32;
typedef unsigned long long u64;

constexpr int NB   = 32;     // batch
constexpr int NN   = 50000;  // boxes per image
constexpr int NC   = 10;     // classes
constexpr int KK   = 512;    // PRE_NMS_TOPK
constexpr int MAXD = 100;    // MAX_DETECTIONS
constexpr int CAP  = 4096;   // LDS candidate capacity for radix select

// output section offsets (floats)
constexpr int OFF_BOX = 0;                       // 32*100*4
constexpr int OFF_SC  = NB * MAXD * 4;           // 12800
constexpr int OFF_LB  = OFF_SC + NB * MAXD;      // 16000
constexpr int OFF_RT  = OFF_LB + NB * MAXD;      // 19200
constexpr int OFF_TR  = OFF_RT + NB * MAXD * 3;  // 28800

__device__ __forceinline__ u32 ord_f32(float s) {
  u32 u = __float_as_uint(s);
  return (u & 0x80000000u) ? ~u : (u | 0x80000000u);
}
__device__ __forceinline__ float unord_f32(u32 o) {
  u32 u = (o & 0x80000000u) ? (o & 0x7FFFFFFFu) : ~o;
  return __uint_as_float(u);
}
// key: high 32 = ordered score (masked to -inf at <=0.01), low 32 = ~idx
// (larger key == better; ties -> smaller original index wins)
__device__ __forceinline__ u64 make_key(float s, u32 i) {
  float sp = (s > 0.01f) ? s : -INFINITY;
  return ((u64)ord_f32(sp) << 32) | (u64)(u32)(~i);
}

// descending bitonic sort of a[0..n) (n = power of 2), nt threads
__device__ inline void bitonic_desc(u64* a, int n, int t, int nt) {
  for (int k = 2; k <= n; k <<= 1) {
    for (int j = k >> 1; j > 0; j >>= 1) {
      for (int i = t; i < n; i += nt) {
        int ixj = i ^ j;
        if (ixj > i) {
          u64 x = a[i], y = a[ixj];
          if (((i & k) == 0) ? (x < y) : (x > y)) { a[i] = y; a[ixj] = x; }
        }
      }
      __syncthreads();
    }
  }
}

// ---------------- Kernel 1: exact top-512 per (b,c) ----------------
__global__ __launch_bounds__(512) void topk_kernel(
    const float* __restrict__ cls, int* __restrict__ out_idx,
    float* __restrict__ out_sc) {
  const int bc = blockIdx.x;
  const int b = bc / NC, c = bc % NC;
  const float* base = cls + (size_t)b * NN * NC + c;
  __shared__ u32 hist[256], suf[256];
  __shared__ int s_d, s_above, s_cnt, s_g;
  __shared__ u64 cand[CAP];
  __shared__ u64 sel[KK];
  const int t = threadIdx.x;

  u64 prefix = 0;
  int pb = 0;          // known prefix bits
  int remaining = KK;  // still needed from the == prefix bucket

  // radix-select digit loop (8-bit digits, MSB first)
  for (;;) {
    __syncthreads();
    if (t < 256) hist[t] = 0;
    __syncthreads();
    const int shift = 64 - pb - 8;
    for (int i = t; i < NN; i += 512) {
      u64 k = make_key(base[(size_t)i * NC], (u32)i);
      if (pb == 0 || (k >> (64 - pb)) == prefix)
        atomicAdd(&hist[(u32)(k >> shift) & 255u], 1u);
    }
    __syncthreads();
    if (t < 256) suf[t] = hist[t];
    __syncthreads();
    for (int s = 1; s < 256; s <<= 1) {  // suffix sums (from top digit down)
      u32 add = 0;
      if (t < 256 && t + s < 256) add = suf[t + s];
      __syncthreads();
      if (t < 256) suf[t] += add;
      __syncthreads();
    }
    if (t < 256) {
      u32 S = suf[t], Sn = (t == 255) ? 0u : suf[t + 1];
      if (S >= (u32)remaining && Sn < (u32)remaining) { s_d = t; s_above = (int)Sn; }
    }
    __syncthreads();
    const int d = s_d;
    remaining -= s_above;
    prefix = (prefix << 8) | (u32)d;
    pb += 8;
    if ((int)hist[d] <= CAP || pb == 64) break;
  }

  // one scan: collect strictly-greater set into sel, == prefix bucket into cand
  if (t == 0) { s_cnt = 0; s_g = 0; }
  __syncthreads();
  const int shift2 = 64 - pb;  // pb >= 8 here, shift2 in [0,56]
  for (int i = t; i < NN; i += 512) {
    u64 k = make_key(base[(size_t)i * NC], (u32)i);
    u64 hi = k >> shift2;
    if (hi > prefix) {
      int p = atomicAdd(&s_g, 1);
      if (p < KK) sel[p] = k;
    } else if (hi == prefix) {
      int p = atomicAdd(&s_cnt, 1);
      if (p < CAP) cand[p] = k;
    }
  }
  __syncthreads();
  const int cnt = min(s_cnt, CAP);
  const int G = min(s_g, KK);
  int npow = 1;
  while (npow < cnt) npow <<= 1;
  for (int i = cnt + t; i < npow; i += 512) cand[i] = 0;
  __syncthreads();
  bitonic_desc(cand, npow, t, 512);
  for (int r = t; r < remaining; r += 512) sel[G + r] = cand[r];
  __syncthreads();
  bitonic_desc(sel, KK, t, 512);

  {
    u64 k = sel[t];
    out_idx[bc * KK + t] = (int)(~(u32)k);
    out_sc[bc * KK + t] = unord_f32((u32)(k >> 32));
  }
}

// ---------------- Kernel 2: greedy NMS per (b,c) ----------------
__global__ __launch_bounds__(512) void nms_kernel(
    const float* __restrict__ boxes, const int* __restrict__ tidx,
    const float* __restrict__ tsc, float* __restrict__ ksc) {
  const int bc = blockIdx.x;
  const int b = bc / NC;
  __shared__ float x1s[KK], y1s[KK], x2s[KK], y2s[KK], ars[KK], scs[KK];
  __shared__ u64 rowm[KK][8];  // 32 KiB: per-row suppression bitmask
  __shared__ unsigned char keepf[KK];
  const int t = threadIdx.x;

  {
    int idx = tidx[bc * KK + t];
    const float4 bx = *(const float4*)(boxes + ((size_t)b * NN + idx) * 4);
    x1s[t] = bx.x; y1s[t] = bx.y; x2s[t] = bx.z; y2s[t] = bx.w;
    ars[t] = (bx.z - bx.x) * (bx.w - bx.y);
    scs[t] = tsc[bc * KK + t];
    keepf[t] = 0;
  }
  __syncthreads();

  {
    const float xi1 = x1s[t], yi1 = y1s[t], xi2 = x2s[t], yi2 = y2s[t], ai = ars[t];
    u64 m[8] = {0, 0, 0, 0, 0, 0, 0, 0};
    for (int j = 0; j < KK; ++j) {
      float ix1 = fmaxf(xi1, x1s[j]);
      float iy1 = fmaxf(yi1, y1s[j]);
      float ix2 = fminf(xi2, x2s[j]);
      float iy2 = fminf(yi2, y2s[j]);
      float iw = fmaxf(ix2 - ix1, 0.0f);
      float ih = fmaxf(iy2 - iy1, 0.0f);
      float inter = iw * ih;
      float uni = ai + ars[j] - inter;
      float iou = (uni > 0.0f) ? (inter / uni) : 0.0f;  // IEEE div, matches numpy
      if (iou > 0.5f) m[j >> 6] |= 1ull << (j & 63);
    }
#pragma unroll
    for (int w = 0; w < 8; ++w) rowm[t][w] = m[w];
  }
  __syncthreads();

  if (t == 0) {
    u64 supp[8] = {0, 0, 0, 0, 0, 0, 0, 0};
    int count = 0;
    for (int i = 0; i < KK; ++i) {
      bool valid = scs[i] > 0.01f;
      bool sup = (supp[i >> 6] >> (i & 63)) & 1ull;
      if (valid && !sup) {
        keepf[i] = 1;
        if (++count == MAXD) break;  // cumsum cap: only first 100 keeps survive
#pragma unroll
        for (int w = 0; w < 8; ++w) supp[w] |= rowm[i][w];
      }
    }
  }
  __syncthreads();
  ksc[bc * KK + t] = keepf[t] ? scs[t] : -INFINITY;
}

// ---------------- Kernel 3: per-image top-100 + gather ----------------
__global__ __launch_bounds__(512) void final_kernel(
    const float* __restrict__ boxes, const float* __restrict__ rot,
    const float* __restrict__ trans, const int* __restrict__ tidx,
    const float* __restrict__ ksc, float* __restrict__ out) {
  const int b = blockIdx.x;
  __shared__ u64 ck[1024];
  __shared__ int cnt;
  const int t = threadIdx.x;
  if (t == 0) cnt = 0;
  __syncthreads();
  for (int j = t; j < NC * KK; j += 512) {
    float s = ksc[b * NC * KK + j];
    if (s != -INFINITY) {  // kept entries only (<=1000 by construction)
      int p = atomicAdd(&cnt, 1);
      if (p < 1024) ck[p] = ((u64)ord_f32(s) << 32) | (u64)(u32)(~(u32)j);
    }
  }
  __syncthreads();
  const int n = min(cnt, 1024);
  int npow = 128;
  while (npow < n) npow <<= 1;
  for (int i = n + t; i < npow; i += 512) ck[i] = 0;
  __syncthreads();
  bitonic_desc(ck, npow, t, 512);

  if (t < MAXD) {
    float b0 = -1.f, b1 = -1.f, b2 = -1.f, b3 = -1.f;
    float os = -1.f, ol = -1.f;
    float r0 = -1.f, r1 = -1.f, r2 = -1.f;
    float t0 = -1.f, t1 = -1.f, t2 = -1.f;
    if (t < n) {
      u64 k = ck[t];
      int j = (int)(~(u32)k);          // flat index c*512 + slot
      int c = j >> 9, slot = j & (KK - 1);
      int idx = tidx[(b * NC + c) * KK + slot];
      os = unord_f32((u32)(k >> 32));
      ol = (float)c;
      const float4 bx = *(const float4*)(boxes + ((size_t)b * NN + idx) * 4);
      b0 = bx.x; b1 = bx.y; b2 = bx.z; b3 = bx.w;
      const float* rp = rot + ((size_t)b * NN + idx) * 3;
      r0 = rp[0]; r1 = rp[1]; r2 = rp[2];
      const float* tp = trans + ((size_t)b * NN + idx) * 3;
      t0 = tp[0]; t1 = tp[1]; t2 = tp[2];
    }
    const int o = b * MAXD + t;
    out[OFF_BOX + (size_t)o * 4 + 0] = b0;
    out[OFF_BOX + (size_t)o * 4 + 1] = b1;
    out[OFF_BOX + (size_t)o * 4 + 2] = b2;
    out[OFF_BOX + (size_t)o * 4 + 3] = b3;
    out[OFF_SC + o] = os;
    out[OFF_LB + o] = ol;  // labels written as float values
    out[OFF_RT + (size_t)o * 3 + 0] = r0;
    out[OFF_RT + (size_t)o * 3 + 1] = r1;
    out[OFF_RT + (size_t)o * 3 + 2] = r2;
    out[OFF_TR + (size_t)o * 3 + 0] = t0;
    out[OFF_TR + (size_t)o * 3 + 1] = t1;
    out[OFF_TR + (size_t)o * 3 + 2] = t2;
  }
}

extern "C" void kernel_launch(void* const* d_in, const int* in_sizes, int n_in,
                              void* d_out, int out_size, void* d_ws, size_t ws_size,
                              hipStream_t stream) {
  const float* boxes = (const float*)d_in[0];
  const float* cls   = (const float*)d_in[1];
  const float* rot   = (const float*)d_in[2];
  const float* trans = (const float*)d_in[3];
  float* out = (float*)d_out;

  int*   tidx = (int*)d_ws;                       // 320*512 i32
  float* tsc  = (float*)(tidx + NB * NC * KK);    // 320*512 f32
  float* ksc  = tsc + NB * NC * KK;               // 320*512 f32

  topk_kernel<<<NB * NC, 512, 0, stream>>>(cls, tidx, tsc);
  nms_kernel<<<NB * NC, 512, 0, stream>>>(boxes, tidx, tsc, ksc);
  final_kernel<<<NB, 512, 0, stream>>>(boxes, rot, trans, tidx, ksc, out);
}

// Round 2
// 267.006 us; speedup vs baseline: 1.4696x; 1.4696x over previous
//
#include <hip/hip_runtime.h>
#include <math.h>

typedef unsigned int u32;
typedef unsigned long long u64;
typedef unsigned short u16;

constexpr int NB   = 32;     // batch
constexpr int NN   = 50000;  // boxes per image
constexpr int NC   = 10;     // classes
constexpr int KK   = 512;    // PRE_NMS_TOPK
constexpr int MAXD = 100;    // MAX_DETECTIONS
constexpr int CAP  = 4096;   // LDS candidate capacity
constexpr int CH   = 2000;   // rows per transpose chunk (50000 = 25*2000)

// output section offsets (floats)
constexpr int OFF_BOX = 0;
constexpr int OFF_SC  = NB * MAXD * 4;
constexpr int OFF_LB  = OFF_SC + NB * MAXD;
constexpr int OFF_RT  = OFF_LB + NB * MAXD;
constexpr int OFF_TR  = OFF_RT + NB * MAXD * 3;

__device__ __forceinline__ u32 ord_f32(float s) {
  u32 u = __float_as_uint(s);
  return (u & 0x80000000u) ? ~u : (u | 0x80000000u);
}
__device__ __forceinline__ float unord_f32(u32 o) {
  u32 u = (o & 0x80000000u) ? (o & 0x7FFFFFFFu) : ~o;
  return __uint_as_float(u);
}
// key: high 32 = ordered masked score, low 32 = ~idx (ties -> lower idx wins)
__device__ __forceinline__ u64 make_key(float s, u32 i) {
  float sp = (s > 0.01f) ? s : -INFINITY;
  return ((u64)ord_f32(sp) << 32) | (u64)(u32)(~i);
}

// descending bitonic sort of a[0..n) (n = power of 2), nt threads
__device__ inline void bitonic_desc(u64* a, int n, int t, int nt) {
  for (int k = 2; k <= n; k <<= 1) {
    for (int j = k >> 1; j > 0; j >>= 1) {
      for (int i = t; i < n; i += nt) {
        int ixj = i ^ j;
        if (ixj > i) {
          u64 x = a[i], y = a[ixj];
          if (((i & k) == 0) ? (x < y) : (x > y)) { a[i] = y; a[ixj] = x; }
        }
      }
      __syncthreads();
    }
  }
}

// ---------- Kernel A: coalesced transpose to 16-bit ordered keys ----------
__global__ __launch_bounds__(512) void transpose_kernel(
    const float* __restrict__ cls, u16* __restrict__ ord16) {
  const int blk = blockIdx.x;
  const int b = blk / 25, ch = blk % 25;
  const float* src = cls + ((size_t)b * NN + (size_t)ch * CH) * NC;
  __shared__ u16 tile[CH * 11];  // pad 10->11 to break bank conflicts
  const int t = threadIdx.x;
  for (int q = t; q < CH * NC / 4; q += 512) {
    float4 v = ((const float4*)src)[q];
    float arr[4] = {v.x, v.y, v.z, v.w};
    const int e = q * 4;
#pragma unroll
    for (int k = 0; k < 4; ++k) {
      float x = arr[k];
      u16 o = (x > 0.01f) ? (u16)(ord_f32(x) >> 16) : (u16)0;
      int ee = e + k, r = ee / 10, c = ee - r * 10;
      tile[r * 11 + c] = o;
    }
  }
  __syncthreads();
  for (int q = t; q < CH * NC / 4; q += 512) {
    const int c = q / (CH / 4);
    const int r = (q - c * (CH / 4)) * 4;
    ushort4 o;
    o.x = tile[(r + 0) * 11 + c];
    o.y = tile[(r + 1) * 11 + c];
    o.z = tile[(r + 2) * 11 + c];
    o.w = tile[(r + 3) * 11 + c];
    ((ushort4*)ord16)[((size_t)(b * NC + c) * NN + (size_t)ch * CH + r) >> 2] = o;
  }
}

// ---------- Kernel B: exact top-512 per (b,c), coalesced ----------
__global__ __launch_bounds__(512) void select_kernel(
    const u16* __restrict__ ord16, const float* __restrict__ cls,
    int* __restrict__ out_idx, float* __restrict__ out_sc) {
  const int bc = blockIdx.x;
  const int b = bc / NC, c = bc % NC;
  const u16* col = ord16 + (size_t)bc * NN;
  const float* sbase = cls + (size_t)b * NN * NC + c;
  __shared__ u32 hist[4096];
  __shared__ u64 cand[CAP];
  __shared__ u64 sel[KK];
  __shared__ int s_cnt, s_g, s_d, s_ab;
  const int t = threadIdx.x;

  for (int i = t; i < 4096; i += 512) hist[i] = 0;
  __syncthreads();
  // pass 1: 12-bit histogram over the contiguous u16 column
  for (int q = t; q < NN / 8; q += 512) {
    uint4 v = ((const uint4*)col)[q];
    u32 w[4] = {v.x, v.y, v.z, v.w};
#pragma unroll
    for (int k = 0; k < 4; ++k) {
      atomicAdd(&hist[(w[k] & 0xFFFFu) >> 4], 1u);
      atomicAdd(&hist[(w[k] >> 16) >> 4], 1u);
    }
  }
  __syncthreads();
  // suffix-sum over 4096 bins (hist[i] = count of digits >= i)
  for (int s = 1; s < 4096; s <<= 1) {
    u32 add[8];
#pragma unroll
    for (int k = 0; k < 8; ++k) {
      int i = t + k * 512;
      add[k] = (i + s < 4096) ? hist[i + s] : 0u;
    }
    __syncthreads();
#pragma unroll
    for (int k = 0; k < 8; ++k) hist[t + k * 512] += add[k];
    __syncthreads();
  }
#pragma unroll
  for (int k = 0; k < 8; ++k) {
    int i = t + k * 512;
    u32 S = hist[i], Sn = (i == 4095) ? 0u : hist[i + 1];
    if (S >= (u32)KK && Sn < (u32)KK) { s_d = i; s_ab = (int)Sn; }
  }
  if (t == 0) { s_cnt = 0; s_g = 0; }
  __syncthreads();
  const u32 prefix = (u32)s_d;
  int remaining = KK - s_ab;
  // pass 2: collect strictly-greater -> sel, == prefix -> cand (exact keys)
  for (int q = t; q < NN / 8; q += 512) {
    uint4 v = ((const uint4*)col)[q];
    u32 w[4] = {v.x, v.y, v.z, v.w};
#pragma unroll
    for (int k = 0; k < 8; ++k) {
      u32 h = (k & 1) ? (w[k >> 1] >> 16) : (w[k >> 1] & 0xFFFFu);
      u32 hi = h >> 4;
      if (hi >= prefix) {
        int i = q * 8 + k;
        u64 key = make_key(sbase[(size_t)i * NC], (u32)i);
        if (hi > prefix) {
          int p = atomicAdd(&s_g, 1);
          if (p < KK) sel[p] = key;
        } else {
          int p = atomicAdd(&s_cnt, 1);
          if (p < CAP) cand[p] = key;
        }
      }
    }
  }
  __syncthreads();
  int cnt = min(s_cnt, CAP);
  int G = min(s_g, KK);
  // in-LDS 8-bit radix refinement on exact keys
  int shift = 64 - 12 - 8;  // bits below the 12-bit prefix
  while (cnt > 1024 && shift >= 0) {
    if (t < 256) hist[t] = 0;
    __syncthreads();
    for (int i = t; i < cnt; i += 512)
      atomicAdd(&hist[(u32)(cand[i] >> shift) & 255u], 1u);
    __syncthreads();
    for (int s = 1; s < 256; s <<= 1) {
      u32 add = 0;
      if (t < 256 && t + s < 256) add = hist[t + s];
      __syncthreads();
      if (t < 256) hist[t] += add;
      __syncthreads();
    }
    if (t < 256) {
      u32 S = hist[t], Sn = (t == 255) ? 0u : hist[t + 1];
      if (S >= (u32)remaining && Sn < (u32)remaining) { s_d = t; s_ab = (int)Sn; }
    }
    __syncthreads();
    const u32 d2 = (u32)s_d;
    const int above = s_ab;
    // partition: > d2 append to sel; == d2 keep in regs
    u64 mine[8];
    int nm = 0;
    for (int i = t; i < cnt; i += 512) {
      u64 k = cand[i];
      u32 dg = (u32)(k >> shift) & 255u;
      if (dg > d2) {
        int p = atomicAdd(&s_g, 1);
        if (p < KK) sel[p] = k;
      } else if (dg == d2) {
        mine[nm++] = k;
      }
    }
    __syncthreads();
    if (t == 0) s_cnt = 0;
    __syncthreads();
    for (int k = 0; k < nm; ++k) {
      int p = atomicAdd(&s_cnt, 1);
      if (p < CAP) cand[p] = mine[k];
    }
    __syncthreads();
    remaining -= above;
    cnt = min(s_cnt, CAP);
    G = min(s_g, KK);
    shift -= 8;
  }
  // sort the small remainder bucket, take top `remaining`
  int npow = 2;
  while (npow < cnt) npow <<= 1;
  for (int i = cnt + t; i < npow; i += 512) cand[i] = 0;
  __syncthreads();
  bitonic_desc(cand, npow, t, 512);
  for (int r = t; r < remaining; r += 512) sel[G + r] = cand[r];
  __syncthreads();
  bitonic_desc(sel, KK, t, 512);
  {
    u64 k = sel[t];
    out_idx[bc * KK + t] = (int)(~(u32)k);
    out_sc[bc * KK + t] = unord_f32((u32)(k >> 32));
  }
}

// ---------------- Kernel 2: greedy NMS per (b,c) ----------------
__global__ __launch_bounds__(512) void nms_kernel(
    const float* __restrict__ boxes, const int* __restrict__ tidx,
    const float* __restrict__ tsc, float* __restrict__ ksc) {
  const int bc = blockIdx.x;
  const int b = bc / NC;
  __shared__ float x1s[KK], y1s[KK], x2s[KK], y2s[KK], ars[KK], scs[KK];
  __shared__ u64 rowm[KK][8];
  __shared__ unsigned char keepf[KK];
  const int t = threadIdx.x;

  {
    int idx = tidx[bc * KK + t];
    const float4 bx = *(const float4*)(boxes + ((size_t)b * NN + idx) * 4);
    x1s[t] = bx.x; y1s[t] = bx.y; x2s[t] = bx.z; y2s[t] = bx.w;
    ars[t] = (bx.z - bx.x) * (bx.w - bx.y);
    scs[t] = tsc[bc * KK + t];
    keepf[t] = 0;
  }
  __syncthreads();

  {
    const float xi1 = x1s[t], yi1 = y1s[t], xi2 = x2s[t], yi2 = y2s[t], ai = ars[t];
    u64 m[8] = {0, 0, 0, 0, 0, 0, 0, 0};
    for (int j = 0; j < KK; ++j) {
      float ix1 = fmaxf(xi1, x1s[j]);
      float iy1 = fmaxf(yi1, y1s[j]);
      float ix2 = fminf(xi2, x2s[j]);
      float iy2 = fminf(yi2, y2s[j]);
      float iw = fmaxf(ix2 - ix1, 0.0f);
      float ih = fmaxf(iy2 - iy1, 0.0f);
      float inter = iw * ih;
      float uni = ai + ars[j] - inter;
      float iou = (uni > 0.0f) ? (inter / uni) : 0.0f;
      if (iou > 0.5f) m[j >> 6] |= 1ull << (j & 63);
    }
#pragma unroll
    for (int w = 0; w < 8; ++w) rowm[t][w] = m[w];
  }
  __syncthreads();

  if (t == 0) {
    u64 supp[8] = {0, 0, 0, 0, 0, 0, 0, 0};
    int count = 0;
    for (int i = 0; i < KK; ++i) {
      bool valid = scs[i] > 0.01f;
      bool sup = (supp[i >> 6] >> (i & 63)) & 1ull;
      if (valid && !sup) {
        keepf[i] = 1;
        if (++count == MAXD) break;
#pragma unroll
        for (int w = 0; w < 8; ++w) supp[w] |= rowm[i][w];
      }
    }
  }
  __syncthreads();
  ksc[bc * KK + t] = keepf[t] ? scs[t] : -INFINITY;
}

// ---------------- Kernel 3: per-image top-100 + gather ----------------
__global__ __launch_bounds__(512) void final_kernel(
    const float* __restrict__ boxes, const float* __restrict__ rot,
    const float* __restrict__ trans, const int* __restrict__ tidx,
    const float* __restrict__ ksc, float* __restrict__ out) {
  const int b = blockIdx.x;
  __shared__ u64 ck[1024];
  __shared__ int cnt;
  const int t = threadIdx.x;
  if (t == 0) cnt = 0;
  __syncthreads();
  for (int j = t; j < NC * KK; j += 512) {
    float s = ksc[b * NC * KK + j];
    if (s != -INFINITY) {
      int p = atomicAdd(&cnt, 1);
      if (p < 1024) ck[p] = ((u64)ord_f32(s) << 32) | (u64)(u32)(~(u32)j);
    }
  }
  __syncthreads();
  const int n = min(cnt, 1024);
  int npow = 128;
  while (npow < n) npow <<= 1;
  for (int i = n + t; i < npow; i += 512) ck[i] = 0;
  __syncthreads();
  bitonic_desc(ck, npow, t, 512);

  if (t < MAXD) {
    float b0 = -1.f, b1 = -1.f, b2 = -1.f, b3 = -1.f;
    float os = -1.f, ol = -1.f;
    float r0 = -1.f, r1 = -1.f, r2 = -1.f;
    float t0 = -1.f, t1 = -1.f, t2 = -1.f;
    if (t < n) {
      u64 k = ck[t];
      int j = (int)(~(u32)k);
      int c = j >> 9, slot = j & (KK - 1);
      int idx = tidx[(b * NC + c) * KK + slot];
      os = unord_f32((u32)(k >> 32));
      ol = (float)c;
      const float4 bx = *(const float4*)(boxes + ((size_t)b * NN + idx) * 4);
      b0 = bx.x; b1 = bx.y; b2 = bx.z; b3 = bx.w;
      const float* rp = rot + ((size_t)b * NN + idx) * 3;
      r0 = rp[0]; r1 = rp[1]; r2 = rp[2];
      const float* tp = trans + ((size_t)b * NN + idx) * 3;
      t0 = tp[0]; t1 = tp[1]; t2 = tp[2];
    }
    const int o = b * MAXD + t;
    out[OFF_BOX + (size_t)o * 4 + 0] = b0;
    out[OFF_BOX + (size_t)o * 4 + 1] = b1;
    out[OFF_BOX + (size_t)o * 4 + 2] = b2;
    out[OFF_BOX + (size_t)o * 4 + 3] = b3;
    out[OFF_SC + o] = os;
    out[OFF_LB + o] = ol;
    out[OFF_RT + (size_t)o * 3 + 0] = r0;
    out[OFF_RT + (size_t)o * 3 + 1] = r1;
    out[OFF_RT + (size_t)o * 3 + 2] = r2;
    out[OFF_TR + (size_t)o * 3 + 0] = t0;
    out[OFF_TR + (size_t)o * 3 + 1] = t1;
    out[OFF_TR + (size_t)o * 3 + 2] = t2;
  }
}

extern "C" void kernel_launch(void* const* d_in, const int* in_sizes, int n_in,
                              void* d_out, int out_size, void* d_ws, size_t ws_size,
                              hipStream_t stream) {
  const float* boxes = (const float*)d_in[0];
  const float* cls   = (const float*)d_in[1];
  const float* rot   = (const float*)d_in[2];
  const float* trans = (const float*)d_in[3];
  float* out = (float*)d_out;

  u16* ord16 = (u16*)d_ws;                               // 32*10*50000 u16 = 32 MB
  int* tidx  = (int*)(ord16 + (size_t)NB * NC * NN);     // 320*512 i32
  float* tsc = (float*)(tidx + NB * NC * KK);
  float* ksc = tsc + NB * NC * KK;

  transpose_kernel<<<NB * 25, 512, 0, stream>>>(cls, ord16);
  select_kernel<<<NB * NC, 512, 0, stream>>>(ord16, cls, tidx, tsc);
  nms_kernel<<<NB * NC, 512, 0, stream>>>(boxes, tidx, tsc, ksc);
  final_kernel<<<NB, 512, 0, stream>>>(boxes, rot, trans, tidx, ksc, out);
}

// Round 3
// 229.859 us; speedup vs baseline: 1.7071x; 1.1616x over previous
//
#include <hip/hip_runtime.h>
#include <math.h>

typedef unsigned int u32;
typedef unsigned long long u64;
typedef unsigned short u16;

constexpr int NB   = 32;     // batch
constexpr int NN   = 50000;  // boxes per image
constexpr int NC   = 10;     // classes
constexpr int KK   = 512;    // PRE_NMS_TOPK
constexpr int MAXD = 100;    // MAX_DETECTIONS
constexpr int CAP  = 4096;   // LDS candidate capacity
constexpr int CH   = 2000;   // rows per transpose chunk (50000 = 25*2000)

// output section offsets (floats)
constexpr int OFF_BOX = 0;
constexpr int OFF_SC  = NB * MAXD * 4;
constexpr int OFF_LB  = OFF_SC + NB * MAXD;
constexpr int OFF_RT  = OFF_LB + NB * MAXD;
constexpr int OFF_TR  = OFF_RT + NB * MAXD * 3;

__device__ __forceinline__ u32 ord_f32(float s) {
  u32 u = __float_as_uint(s);
  return (u & 0x80000000u) ? ~u : (u | 0x80000000u);
}
__device__ __forceinline__ float unord_f32(u32 o) {
  u32 u = (o & 0x80000000u) ? (o & 0x7FFFFFFFu) : ~o;
  return __uint_as_float(u);
}
// key: high 32 = ordered masked score, low 32 = ~idx (ties -> lower idx wins)
__device__ __forceinline__ u64 make_key(float s, u32 i) {
  float sp = (s > 0.01f) ? s : -INFINITY;
  return ((u64)ord_f32(sp) << 32) | (u64)(u32)(~i);
}

// descending bitonic sort of a[0..n) (n = power of 2), nt threads
__device__ inline void bitonic_desc(u64* a, int n, int t, int nt) {
  for (int k = 2; k <= n; k <<= 1) {
    for (int j = k >> 1; j > 0; j >>= 1) {
      for (int i = t; i < n; i += nt) {
        int ixj = i ^ j;
        if (ixj > i) {
          u64 x = a[i], y = a[ixj];
          if (((i & k) == 0) ? (x < y) : (x > y)) { a[i] = y; a[ixj] = x; }
        }
      }
      __syncthreads();
    }
  }
}

// ---------- Kernel A: coalesced transpose to 16-bit ordered keys ----------
__global__ __launch_bounds__(512) void transpose_kernel(
    const float* __restrict__ cls, u16* __restrict__ ord16) {
  const int blk = blockIdx.x;
  const int b = blk / 25, ch = blk % 25;
  const float* src = cls + ((size_t)b * NN + (size_t)ch * CH) * NC;
  __shared__ u16 tile[CH * 11];  // pad 10->11 to break bank conflicts
  const int t = threadIdx.x;
  for (int q = t; q < CH * NC / 4; q += 512) {
    float4 v = ((const float4*)src)[q];
    float arr[4] = {v.x, v.y, v.z, v.w};
    const int e = q * 4;
#pragma unroll
    for (int k = 0; k < 4; ++k) {
      float x = arr[k];
      u16 o = (x > 0.01f) ? (u16)(ord_f32(x) >> 16) : (u16)0;
      int ee = e + k, r = ee / 10, c = ee - r * 10;
      tile[r * 11 + c] = o;
    }
  }
  __syncthreads();
  for (int q = t; q < CH * NC / 4; q += 512) {
    const int c = q / (CH / 4);
    const int r = (q - c * (CH / 4)) * 4;
    ushort4 o;
    o.x = tile[(r + 0) * 11 + c];
    o.y = tile[(r + 1) * 11 + c];
    o.z = tile[(r + 2) * 11 + c];
    o.w = tile[(r + 3) * 11 + c];
    ((ushort4*)ord16)[((size_t)(b * NC + c) * NN + (size_t)ch * CH + r) >> 2] = o;
  }
}

// ---------- Kernel B: exact top-512 per (b,c), coalesced ----------
__global__ __launch_bounds__(512) void select_kernel(
    const u16* __restrict__ ord16, const float* __restrict__ cls,
    int* __restrict__ out_idx, float* __restrict__ out_sc) {
  const int bc = blockIdx.x;
  const int b = bc / NC, c = bc % NC;
  const u16* col = ord16 + (size_t)bc * NN;
  const float* sbase = cls + (size_t)b * NN * NC + c;
  __shared__ u32 hist[4096];
  __shared__ u64 cand[CAP];
  __shared__ u64 sel[KK];
  __shared__ int s_cnt, s_g, s_d, s_ab;
  const int t = threadIdx.x;

  for (int i = t; i < 4096; i += 512) hist[i] = 0;
  __syncthreads();
  // pass 1: 12-bit histogram over the contiguous u16 column
  for (int q = t; q < NN / 8; q += 512) {
    uint4 v = ((const uint4*)col)[q];
    u32 w[4] = {v.x, v.y, v.z, v.w};
#pragma unroll
    for (int k = 0; k < 4; ++k) {
      atomicAdd(&hist[(w[k] & 0xFFFFu) >> 4], 1u);
      atomicAdd(&hist[(w[k] >> 16) >> 4], 1u);
    }
  }
  __syncthreads();
  // suffix-sum over 4096 bins (hist[i] = count of digits >= i)
  for (int s = 1; s < 4096; s <<= 1) {
    u32 add[8];
#pragma unroll
    for (int k = 0; k < 8; ++k) {
      int i = t + k * 512;
      add[k] = (i + s < 4096) ? hist[i + s] : 0u;
    }
    __syncthreads();
#pragma unroll
    for (int k = 0; k < 8; ++k) hist[t + k * 512] += add[k];
    __syncthreads();
  }
#pragma unroll
  for (int k = 0; k < 8; ++k) {
    int i = t + k * 512;
    u32 S = hist[i], Sn = (i == 4095) ? 0u : hist[i + 1];
    if (S >= (u32)KK && Sn < (u32)KK) { s_d = i; s_ab = (int)Sn; }
  }
  if (t == 0) { s_cnt = 0; s_g = 0; }
  __syncthreads();
  const u32 prefix = (u32)s_d;
  int remaining = KK - s_ab;
  // pass 2: collect strictly-greater -> sel, == prefix -> cand (exact keys)
  for (int q = t; q < NN / 8; q += 512) {
    uint4 v = ((const uint4*)col)[q];
    u32 w[4] = {v.x, v.y, v.z, v.w};
#pragma unroll
    for (int k = 0; k < 8; ++k) {
      u32 h = (k & 1) ? (w[k >> 1] >> 16) : (w[k >> 1] & 0xFFFFu);
      u32 hi = h >> 4;
      if (hi >= prefix) {
        int i = q * 8 + k;
        u64 key = make_key(sbase[(size_t)i * NC], (u32)i);
        if (hi > prefix) {
          int p = atomicAdd(&s_g, 1);
          if (p < KK) sel[p] = key;
        } else {
          int p = atomicAdd(&s_cnt, 1);
          if (p < CAP) cand[p] = key;
        }
      }
    }
  }
  __syncthreads();
  int cnt = min(s_cnt, CAP);
  int G = min(s_g, KK);
  // in-LDS 8-bit radix refinement on exact keys
  int shift = 64 - 12 - 8;  // bits below the 12-bit prefix
  while (cnt > 1024 && shift >= 0) {
    if (t < 256) hist[t] = 0;
    __syncthreads();
    for (int i = t; i < cnt; i += 512)
      atomicAdd(&hist[(u32)(cand[i] >> shift) & 255u], 1u);
    __syncthreads();
    for (int s = 1; s < 256; s <<= 1) {
      u32 add = 0;
      if (t < 256 && t + s < 256) add = hist[t + s];
      __syncthreads();
      if (t < 256) hist[t] += add;
      __syncthreads();
    }
    if (t < 256) {
      u32 S = hist[t], Sn = (t == 255) ? 0u : hist[t + 1];
      if (S >= (u32)remaining && Sn < (u32)remaining) { s_d = t; s_ab = (int)Sn; }
    }
    __syncthreads();
    const u32 d2 = (u32)s_d;
    const int above = s_ab;
    u64 mine[8];
    int nm = 0;
    for (int i = t; i < cnt; i += 512) {
      u64 k = cand[i];
      u32 dg = (u32)(k >> shift) & 255u;
      if (dg > d2) {
        int p = atomicAdd(&s_g, 1);
        if (p < KK) sel[p] = k;
      } else if (dg == d2) {
        mine[nm++] = k;
      }
    }
    __syncthreads();
    if (t == 0) s_cnt = 0;
    __syncthreads();
    for (int k = 0; k < nm; ++k) {
      int p = atomicAdd(&s_cnt, 1);
      if (p < CAP) cand[p] = mine[k];
    }
    __syncthreads();
    remaining -= above;
    cnt = min(s_cnt, CAP);
    G = min(s_g, KK);
    shift -= 8;
  }
  int npow = 2;
  while (npow < cnt) npow <<= 1;
  for (int i = cnt + t; i < npow; i += 512) cand[i] = 0;
  __syncthreads();
  bitonic_desc(cand, npow, t, 512);
  for (int r = t; r < remaining; r += 512) sel[G + r] = cand[r];
  __syncthreads();
  bitonic_desc(sel, KK, t, 512);
  {
    u64 k = sel[t];
    out_idx[bc * KK + t] = (int)(~(u32)k);
    out_sc[bc * KK + t] = unord_f32((u32)(k >> 32));
  }
}

// ---------------- Kernel 2: greedy NMS per (b,c) ----------------
// Register-held j-boxes + __ballot mask build + division-free exact compare.
__global__ __launch_bounds__(512) void nms_kernel(
    const float* __restrict__ boxes, const int* __restrict__ tidx,
    const float* __restrict__ tsc, float* __restrict__ ksc) {
  const int bc = blockIdx.x;
  const int b = bc / NC;
  __shared__ float4 bx4[KK];   // 8 KiB
  __shared__ float ars[KK];    // 2 KiB
  __shared__ float scs[KK];    // 2 KiB
  __shared__ u64 rowm[KK][8];  // 32 KiB suppression bitmasks
  __shared__ unsigned char keepf[KK];
  const int t = threadIdx.x;
  const int lane = t & 63;
  const int wv = t >> 6;  // 8 waves

  {
    int idx = tidx[bc * KK + t];
    const float4 bx = *(const float4*)(boxes + ((size_t)b * NN + idx) * 4);
    bx4[t] = bx;
    ars[t] = (bx.z - bx.x) * (bx.w - bx.y);
    scs[t] = tsc[bc * KK + t];
    keepf[t] = 0;
  }
  __syncthreads();

  // lane l holds j-boxes for j = q*64 + l, q = 0..7 (registers)
  float jx1[8], jy1[8], jx2[8], jy2[8], jar[8];
#pragma unroll
  for (int q = 0; q < 8; ++q) {
    float4 bb = bx4[q * 64 + lane];
    jx1[q] = bb.x; jy1[q] = bb.y; jx2[q] = bb.z; jy2[q] = bb.w;
    jar[q] = ars[q * 64 + lane];
  }

  // RN32(inter/uni) > 0.5  <=>  inter/uni > 0.5 + 2^-25 (exact; tie->even=0.5)
  // sign(inter - C*uni) computed exactly via one f64 fma (50-bit product <= 53)
  const double C = 0x1.000001p-1;  // 0.5 + 2^-25

  // each wave builds mask rows [wv*64, wv*64+64)
  for (int r = 0; r < 64; ++r) {
    const int i = wv * 64 + r;
    const float4 bi = bx4[i];  // wave-uniform broadcast read
    const float ai = ars[i];
#pragma unroll
    for (int q = 0; q < 8; ++q) {
      float ix1 = fmaxf(bi.x, jx1[q]);
      float iy1 = fmaxf(bi.y, jy1[q]);
      float ix2 = fminf(bi.z, jx2[q]);
      float iy2 = fminf(bi.w, jy2[q]);
      float iw = fmaxf(ix2 - ix1, 0.0f);
      float ih = fmaxf(iy2 - iy1, 0.0f);
      float inter = iw * ih;
      float uni = ai + jar[q] - inter;
      bool sup = (uni > 0.0f) && (fma(-C, (double)uni, (double)inter) > 0.0);
      u64 w = __ballot(sup);
      if (lane == q) rowm[i][q] = w;
    }
  }
  __syncthreads();

  if (t == 0) {
    u64 supp[8] = {0, 0, 0, 0, 0, 0, 0, 0};
    int count = 0;
    for (int i = 0; i < KK; ++i) {
      bool valid = scs[i] > 0.01f;
      bool sup = (supp[i >> 6] >> (i & 63)) & 1ull;
      if (valid && !sup) {
        keepf[i] = 1;
        if (++count == MAXD) break;  // cumsum cap
#pragma unroll
        for (int w = 0; w < 8; ++w) supp[w] |= rowm[i][w];
      }
    }
  }
  __syncthreads();
  ksc[bc * KK + t] = keepf[t] ? scs[t] : -INFINITY;
}

// ---------------- Kernel 3: per-image top-100 + gather ----------------
__global__ __launch_bounds__(512) void final_kernel(
    const float* __restrict__ boxes, const float* __restrict__ rot,
    const float* __restrict__ trans, const int* __restrict__ tidx,
    const float* __restrict__ ksc, float* __restrict__ out) {
  const int b = blockIdx.x;
  __shared__ u64 ck[1024];
  __shared__ int cnt;
  const int t = threadIdx.x;
  if (t == 0) cnt = 0;
  __syncthreads();
  for (int j = t; j < NC * KK; j += 512) {
    float s = ksc[b * NC * KK + j];
    if (s != -INFINITY) {
      int p = atomicAdd(&cnt, 1);
      if (p < 1024) ck[p] = ((u64)ord_f32(s) << 32) | (u64)(u32)(~(u32)j);
    }
  }
  __syncthreads();
  const int n = min(cnt, 1024);
  int npow = 128;
  while (npow < n) npow <<= 1;
  for (int i = n + t; i < npow; i += 512) ck[i] = 0;
  __syncthreads();
  bitonic_desc(ck, npow, t, 512);

  if (t < MAXD) {
    float b0 = -1.f, b1 = -1.f, b2 = -1.f, b3 = -1.f;
    float os = -1.f, ol = -1.f;
    float r0 = -1.f, r1 = -1.f, r2 = -1.f;
    float t0 = -1.f, t1 = -1.f, t2 = -1.f;
    if (t < n) {
      u64 k = ck[t];
      int j = (int)(~(u32)k);
      int c = j >> 9, slot = j & (KK - 1);
      int idx = tidx[(b * NC + c) * KK + slot];
      os = unord_f32((u32)(k >> 32));
      ol = (float)c;
      const float4 bx = *(const float4*)(boxes + ((size_t)b * NN + idx) * 4);
      b0 = bx.x; b1 = bx.y; b2 = bx.z; b3 = bx.w;
      const float* rp = rot + ((size_t)b * NN + idx) * 3;
      r0 = rp[0]; r1 = rp[1]; r2 = rp[2];
      const float* tp = trans + ((size_t)b * NN + idx) * 3;
      t0 = tp[0]; t1 = tp[1]; t2 = tp[2];
    }
    const int o = b * MAXD + t;
    out[OFF_BOX + (size_t)o * 4 + 0] = b0;
    out[OFF_BOX + (size_t)o * 4 + 1] = b1;
    out[OFF_BOX + (size_t)o * 4 + 2] = b2;
    out[OFF_BOX + (size_t)o * 4 + 3] = b3;
    out[OFF_SC + o] = os;
    out[OFF_LB + o] = ol;
    out[OFF_RT + (size_t)o * 3 + 0] = r0;
    out[OFF_RT + (size_t)o * 3 + 1] = r1;
    out[OFF_RT + (size_t)o * 3 + 2] = r2;
    out[OFF_TR + (size_t)o * 3 + 0] = t0;
    out[OFF_TR + (size_t)o * 3 + 1] = t1;
    out[OFF_TR + (size_t)o * 3 + 2] = t2;
  }
}

extern "C" void kernel_launch(void* const* d_in, const int* in_sizes, int n_in,
                              void* d_out, int out_size, void* d_ws, size_t ws_size,
                              hipStream_t stream) {
  const float* boxes = (const float*)d_in[0];
  const float* cls   = (const float*)d_in[1];
  const float* rot   = (const float*)d_in[2];
  const float* trans = (const float*)d_in[3];
  float* out = (float*)d_out;

  u16* ord16 = (u16*)d_ws;                             // 32 MB
  int* tidx  = (int*)(ord16 + (size_t)NB * NC * NN);
  float* tsc = (float*)(tidx + NB * NC * KK);
  float* ksc = tsc + NB * NC * KK;

  transpose_kernel<<<NB * 25, 512, 0, stream>>>(cls, ord16);
  select_kernel<<<NB * NC, 512, 0, stream>>>(ord16, cls, tidx, tsc);
  nms_kernel<<<NB * NC, 512, 0, stream>>>(boxes, tidx, tsc, ksc);
  final_kernel<<<NB, 512, 0, stream>>>(boxes, rot, trans, tidx, ksc, out);
}